// Round 14
// baseline (4138.888 us; speedup 1.0000x reference)
//
#include <hip/hip_runtime.h>
#include <math.h>

#define BB 2048
#define TT 512
#define NFEAT 25
#define UNITS 300
#define RPB 16
#define NBLK (BB/RPB)    // 128
#define NT 512
#define NKS 11           // ks0 = gates (bf16), ks1-10 = h (fp8)
#define TPW 10           // tiles per wave (80 tiles / 8 waves)
#define AROW 360         // Abf row stride (shorts); cols: 0-23 g, 24 comb, 32..331 h
#define F8ROW 352        // Af8 row stride (bytes); h at 32..331
#define GROW 72

#define OFF_B0 0                     // bf16 ks0 B: [wave][tile][512] shorts
#define SZ_B0  (8*TPW*512)           // 40960
#define OFF_M1 (OFF_B0 + SZ_B0)
#define SZ_M1  (4*2*512)
#define OFF_M2 (OFF_M1 + SZ_M1)
#define SZ_M2  (2*2*512)
#define OFF_H  (OFF_M2 + SZ_M2)
#define SZ_H   (2*NKS*512)
#define OFF_F8 (OFF_H + SZ_H)        // short offset where fp8 byte region begins
#define SZ_F8B (8*100*512)           // 409600 bytes: [wave][ks1-10][tile][512] bytes
#define SW_SZ  (SZ_M1 + SZ_M2 + SZ_H)
#define SWM1   0
#define SWM2   (SZ_M1)
#define SWH    (SZ_M1 + SZ_M2)

typedef __attribute__((ext_vector_type(4))) float f32x4;
typedef __attribute__((ext_vector_type(8))) short bf16x8;

static __device__ __forceinline__ unsigned short f2bf(float f) {
    union { float f; unsigned u; } x; x.f = f;
    unsigned r = (x.u + 0x7fffu + ((x.u >> 16) & 1u)) >> 16;
    return (unsigned short)r;
}
static __device__ __forceinline__ unsigned char f2f8(float f) {
    return (unsigned char)(__builtin_amdgcn_cvt_pk_fp8_f32(f, 0.f, 0, false) & 0xff);
}
static __device__ __forceinline__ float ftanh(float v) {
    float e = __builtin_amdgcn_exp2f(v * 2.8853900817779268f);
    return 1.f - 2.f * __builtin_amdgcn_rcpf(e + 1.f);
}

// gate-interleaved z columns: col' = 4*u + gate  (oc = gate*300 + u)
static __device__ __forceinline__ int zcol(int c) { return (c & 3) * 300 + (c >> 2); }

// ks0 bf16 B: [wave][tile][512]; k = kg*8+j in 0..31 (wk rows 0..24, rest 0)
__global__ __launch_bounds__(256) void conv_b0(
    const float* __restrict__ wk, unsigned short* __restrict__ dst)
{
    int idx = blockIdx.x * 256 + threadIdx.x;
    if (idx >= SZ_B0) return;
    int j = idx & 7, n = (idx >> 3) & 15, kg = (idx >> 7) & 3, q = idx >> 9;
    int i = q % TPW, w = q / TPW;
    int k = kg * 8 + j, c = (w + 8 * i) * 16 + n;
    float v = (k < 25 && c < 1200) ? wk[k * 1200 + zcol(c)] : 0.f;
    dst[OFF_B0 + idx] = f2bf(v);
}

// fp8 h-part B: [wave][ks1..10][tile][512] bytes; k = ks*32+kg*8+j, u = k-32
__global__ __launch_bounds__(256) void conv_b8(
    const float* __restrict__ wr, unsigned char* __restrict__ dst8)
{
    int idx = blockIdx.x * 256 + threadIdx.x;
    if (idx >= SZ_F8B) return;
    int j = idx & 7, n = (idx >> 3) & 15, kg = (idx >> 7) & 3, q = idx >> 9;
    int i = q % TPW, ks1 = (q / TPW) % 10, w = q / 100;
    int k = (ks1 + 1) * 32 + kg * 8 + j, c = (w + 8 * i) * 16 + n;
    float v = (k >= 32 && k < 332 && c < 1200) ? wr[(k - 32) * 1200 + zcol(c)] : 0.f;
    dst8[idx] = f2f8(v);
}

__global__ __launch_bounds__(256) void conv_gen(
    const float* __restrict__ W, unsigned short* __restrict__ dst,
    int K, int N, int nks, int total)
{
    int idx = blockIdx.x * 256 + threadIdx.x;
    if (idx >= total) return;
    int j = idx & 7, n = (idx >> 3) & 15, kg = (idx >> 7) & 3, qq = idx >> 9;
    int ks = qq % nks, nt = qq / nks;
    int k = ks * 32 + kg * 8 + j, col = nt * 16 + n;
    float v = (k < K && col < N) ? W[k * N + col] : 0.f;
    dst[idx] = f2bf(v);
}

// heads B: K'=352, h at k=32..331 (u=k-32); ks0 all zero (skipped)
__global__ __launch_bounds__(256) void conv_heads(
    const float* __restrict__ wa, const float* __restrict__ wm,
    const float* __restrict__ wsg, unsigned short* __restrict__ dst)
{
    int idx = blockIdx.x * 256 + threadIdx.x;
    if (idx >= SZ_H) return;
    int j = idx & 7, n = (idx >> 3) & 15, kg = (idx >> 7) & 3, qq = idx >> 9;
    int ks = qq % NKS, nt = qq / NKS;
    int k = ks * 32 + kg * 8 + j, col = nt * 16 + n;
    float v = 0.f;
    if (k >= 32 && k < 332 && col < 24) {
        int u = k - 32, h = col >> 3, m = col & 7;
        const float* W = (h == 0) ? wa : (h == 1) ? wm : wsg;
        v = W[u * 8 + m];
    }
    dst[OFF_H + idx] = f2bf(v);
}

#define MFMA   __builtin_amdgcn_mfma_f32_16x16x32_bf16
#define MFMA8  __builtin_amdgcn_mfma_f32_16x16x32_fp8_fp8

__global__ __launch_bounds__(NT, 2)
void dilstm(
    const float* __restrict__ x,
    const unsigned short* __restrict__ wf,
    const float* __restrict__ bz,
    const float* __restrict__ b1v,
    const float* __restrict__ b2v,
    const float* __restrict__ ba,
    const float* __restrict__ bm,
    const float* __restrict__ bs,
    float* __restrict__ out)
{
    __shared__ unsigned short Abf[2][RPB][AROW];           // bf16 A: gates 0-24, h 32-331
    __shared__ __attribute__((aligned(16))) unsigned char Af8[2][RPB][F8ROW]; // fp8 h
    __shared__ unsigned short Gbf[RPB][GROW];
    __shared__ unsigned short G1b[RPB][GROW];
    __shared__ float Sc[RPB][24];
    __shared__ float BzS[1280];
    __shared__ float B1S[64];
    __shared__ float B2S[32];
    __shared__ float Zw[8][2][16][20];                     // per-wave z staging (dbuf)
    __shared__ unsigned short SW[SW_SZ];

    const int t = threadIdx.x;
    const int lane = t & 63, wv = t >> 6;
    const int arow = lane & 15, akg = lane >> 4;
    const int crow0 = akg * 4;
    const int u_l = lane & 3, rr = lane >> 2;
    const int row0 = blockIdx.x * RPB;

    for (int i = t; i < 2 * RPB * AROW; i += NT) ((unsigned short*)Abf)[i] = 0;
    for (int i = t; i < 2 * RPB * F8ROW; i += NT) ((unsigned char*)Af8)[i] = 0;
    for (int i = t; i < RPB * GROW; i += NT) { ((unsigned short*)Gbf)[i] = 0; ((unsigned short*)G1b)[i] = 0; }
    for (int i = t; i < SW_SZ; i += NT) SW[i] = wf[OFF_M1 + i];
    for (int i = t; i < 1280; i += NT)
        BzS[i] = (i < 1200) ? bz[zcol(i)] : 0.f;
    if (t < 64) B1S[t] = (t < 50) ? b1v[t] : 0.f;
    else if (t < 96) B2S[t - 64] = (t - 64 < 24) ? b2v[t - 64] : 0.f;

    float hbias = 0.f;
    {
        int c1 = wv * 16 + arow;
        if (wv < 2 && c1 < 24)
            hbias = (c1 < 8) ? ba[c1] : (c1 < 16) ? bm[c1 - 8] : bs[c1 - 16];
    }

    float creg[TPW];
    #pragma unroll
    for (int i = 0; i < TPW; ++i) creg[i] = 0.f;

    const unsigned short* bw0 = wf + OFF_B0 + wv * (TPW * 512) + (lane << 3);
    const unsigned char*  bw8 = (const unsigned char*)(wf + OFF_F8) + (size_t)wv * (100 * 512) + (lane << 3);

    const int rA = t / 25, eA = t - (t / 25) * 25;
    float combreg = 0.f, xreg = 0.f;
    if (t < RPB * NFEAT) xreg = x[((size_t)(row0 + rA) * TT) * NFEAT + eA];
    __syncthreads();

    // initial gate-input build (prev = 0)
    if (t < RPB * NFEAT) {
        if (eA < 24) {
            Gbf[rA][eA] = f2bf(xreg);
        } else {
            float comb = xreg;
            combreg = comb;
            float denom = fmaxf(comb, 1e-8f);
            Gbf[rA][24] = f2bf(xreg / denom);
            Abf[0][rA][24] = f2bf(comb);
        }
    }
    __syncthreads();

    for (int ts = 0; ts < TT; ++ts) {
        const int p = ts & 1;

        // ================= P_A: wave0 MLP1+MLP2 (in-wave) || all: fp8 h-part =================
        f32x4 acc[TPW];
        #pragma unroll
        for (int i = 0; i < TPW; ++i) acc[i] = (f32x4){0.f, 0.f, 0.f, 0.f};

        if (wv == 0) {
            // MLP1: all 4 col-tiles, serial in wave 0
            bf16x8 ga0 = *(const bf16x8*)&Gbf[arow][akg * 8];
            bf16x8 ga1 = *(const bf16x8*)&Gbf[arow][32 + akg * 8];
            #pragma unroll
            for (int ct = 0; ct < 4; ++ct) {
                bf16x8 b0 = *(const bf16x8*)&SW[SWM1 + (ct * 2 + 0) * 512 + (lane << 3)];
                bf16x8 b1 = *(const bf16x8*)&SW[SWM1 + (ct * 2 + 1) * 512 + (lane << 3)];
                f32x4 a1c = {0.f, 0.f, 0.f, 0.f};
                a1c = MFMA(ga0, b0, a1c, 0, 0, 0);
                a1c = MFMA(ga1, b1, a1c, 0, 0, 0);
                int col = ct * 16 + arow;
                if (col < 50) {
                    #pragma unroll
                    for (int rg = 0; rg < 4; ++rg)
                        G1b[crow0 + rg][col] = f2bf(fmaxf(a1c[rg] + B1S[col], 0.f));
                }
            }
            // MLP2: 2 col-tiles -> gates into Abf[p][.][0..23]
            bf16x8 ha0 = *(const bf16x8*)&G1b[arow][akg * 8];
            bf16x8 ha1 = *(const bf16x8*)&G1b[arow][32 + akg * 8];
            #pragma unroll
            for (int ct = 0; ct < 2; ++ct) {
                bf16x8 b0 = *(const bf16x8*)&SW[SWM2 + (ct * 2 + 0) * 512 + (lane << 3)];
                bf16x8 b1 = *(const bf16x8*)&SW[SWM2 + (ct * 2 + 1) * 512 + (lane << 3)];
                f32x4 a2c = {0.f, 0.f, 0.f, 0.f};
                a2c = MFMA(ha0, b0, a2c, 0, 0, 0);
                a2c = MFMA(ha1, b1, a2c, 0, 0, 0);
                int col = ct * 16 + arow;
                if (col < 24) {
                    #pragma unroll
                    for (int rg = 0; rg < 4; ++rg)
                        Abf[p][crow0 + rg][col] = f2bf(a2c[rg] + B2S[col]);
                }
            }
        }

        // x prefetch: HBM latency drains under the GEMM
        if (t < RPB * NFEAT && ts + 1 < TT)
            xreg = x[((size_t)(row0 + rA) * TT + (ts + 1)) * NFEAT + eA];

        // fp8 h-part (ks1-10), software-pipelined depth 2, one running pointer
        {
            const unsigned char* af8p = &Af8[p][0][0] + arow * F8ROW + akg * 8;
            const unsigned char* bp = bw8;
            long long bbA[TPW], bbB[TPW];
            #pragma unroll
            for (int i = 0; i < TPW; ++i)
                bbA[i] = *(const long long*)(bp + i * 512);
            #pragma unroll 1
            for (int pr = 0; pr < 5; ++pr) {
                const int ks = 2 * pr + 1;
                #pragma unroll
                for (int i = 0; i < TPW; ++i)
                    bbB[i] = *(const long long*)(bp + 5120 + i * 512);
                long long a8a = *(const long long*)(af8p + ks * 32);
                #pragma unroll
                for (int i = 0; i < TPW; ++i)
                    acc[i] = MFMA8(a8a, bbA[i], acc[i], 0, 0, 0);
                if (pr < 4) {
                    #pragma unroll
                    for (int i = 0; i < TPW; ++i)
                        bbA[i] = *(const long long*)(bp + 10240 + i * 512);
                }
                long long a8b = *(const long long*)(af8p + ks * 32 + 32);
                #pragma unroll
                for (int i = 0; i < TPW; ++i)
                    acc[i] = MFMA8(a8b, bbB[i], acc[i], 0, 0, 0);
                bp += 10240;
            }
        }
        __syncthreads();

        // ================= P_B: ks0 (gates, bf16) + LDS-staged cell epilogue =================
        {
            bf16x8 bb0[TPW];
            #pragma unroll
            for (int i = 0; i < TPW; ++i)
                bb0[i] = *(const bf16x8*)(bw0 + i * 512);
            bf16x8 aA = *(const bf16x8*)&Abf[p][arow][akg * 8];
            #pragma unroll
            for (int i = 0; i < TPW; ++i)
                acc[i] = MFMA(aA, bb0[i], acc[i], 0, 0, 0);

            // epilogue: per-wave LDS gate-regroup, double-buffered
            *(f32x4*)&Zw[wv][0][arow][crow0] = acc[0];
            #pragma unroll
            for (int i = 0; i < TPW; ++i) {
                if (i + 1 < TPW)
                    *(f32x4*)&Zw[wv][(i + 1) & 1][arow][crow0] = acc[i + 1];
                f32x4 bz4 = *(const f32x4*)&BzS[(wv + 8 * i) * 16 + 4 * u_l];
                const float* zp = &Zw[wv][i & 1][4 * u_l][rr];
                float zi = zp[0]  + bz4[0];
                float zf = zp[20] + bz4[1];
                float zc = zp[40] + bz4[2];
                float zo = zp[60] + bz4[3];
                if (wv + 8 * i < 75) {
                    float ig = fminf(fmaxf(0.2f * zi + 0.5f, 0.f), 1.f);
                    float fg = fminf(fmaxf(0.2f * zf + 0.5f, 0.f), 1.f);
                    float og = fminf(fmaxf(0.2f * zo + 0.5f, 0.f), 1.f);
                    float cn = fg * creg[i] + ig * ftanh(zc);
                    creg[i] = cn;
                    float hn = og * ftanh(cn);
                    int hc = 32 + (wv + 8 * i) * 4 + u_l;
                    Abf[p ^ 1][rr][hc] = f2bf(hn);
                    Af8[p ^ 1][rr][hc] = f2f8(hn);
                }
            }
        }
        __syncthreads();

        // ================= P_C: heads (waves 0-1), ks1-10 bf16 =================
        if (wv < 2) {
            f32x4 acc3 = {0.f, 0.f, 0.f, 0.f};
            #pragma unroll
            for (int ks = 1; ks < NKS; ++ks) {
                bf16x8 a = *(const bf16x8*)&Abf[p ^ 1][arow][ks * 32 + akg * 8];
                bf16x8 b = *(const bf16x8*)&SW[SWH + (wv * NKS + ks) * 512 + (lane << 3)];
                acc3 = MFMA(a, b, acc3, 0, 0, 0);
            }
            int col = wv * 16 + arow;
            if (col < 24) {
                #pragma unroll
                for (int rg = 0; rg < 4; ++rg)
                    Sc[crow0 + rg][col] = acc3[rg] + hbias;
            }
        }
        __syncthreads();

        // ================= P_D: softmax/nnelu + out + next-step gate input =================
        if (t < RPB * NFEAT) {
            float v;
            if (eA < 8) {
                float mx = Sc[rA][0];
                #pragma unroll
                for (int m = 1; m < 8; ++m) mx = fmaxf(mx, Sc[rA][m]);
                float sum = 0.f;
                #pragma unroll
                for (int m = 0; m < 8; ++m)
                    sum += __builtin_amdgcn_exp2f((Sc[rA][m] - mx) * 1.4426950408889634f);
                v = __builtin_amdgcn_exp2f((Sc[rA][eA] - mx) * 1.4426950408889634f) / sum;
            } else if (eA < 16) {
                v = Sc[rA][eA];
            } else if (eA < 24) {
                float s = Sc[rA][eA];
                v = (s > 0.f) ? (1.f + s) : __builtin_amdgcn_exp2f(s * 1.4426950408889634f);
            } else {
                v = combreg;
            }
            out[((size_t)(row0 + rA) * TT + ts) * NFEAT + eA] = v;
            if (eA < 24) {
                Gbf[rA][eA]      = f2bf(xreg);
                Gbf[rA][25 + eA] = f2bf(v);
            } else {
                float comb = xreg + combreg;
                float denom = fmaxf(comb, 1e-8f);
                Gbf[rA][24] = f2bf(xreg / denom);
                Gbf[rA][49] = f2bf(combreg / denom);
                Abf[p ^ 1][rA][24] = f2bf(comb);
                combreg = comb;
            }
        }
        __syncthreads();
    }
}

extern "C" void kernel_launch(void* const* d_in, const int* in_sizes, int n_in,
                              void* d_out, int out_size, void* d_ws, size_t ws_size,
                              hipStream_t stream) {
    const float* x   = (const float*)d_in[0];
    const float* wk  = (const float*)d_in[1];
    const float* wr  = (const float*)d_in[2];
    const float* bz  = (const float*)d_in[3];
    const float* w1  = (const float*)d_in[4];
    const float* b1  = (const float*)d_in[5];
    const float* w2  = (const float*)d_in[6];
    const float* b2  = (const float*)d_in[7];
    const float* wa  = (const float*)d_in[8];
    const float* ba  = (const float*)d_in[9];
    const float* wm  = (const float*)d_in[10];
    const float* bm  = (const float*)d_in[11];
    const float* wsg = (const float*)d_in[12];
    const float* bs  = (const float*)d_in[13];
    float* out = (float*)d_out;
    unsigned short* wf = (unsigned short*)d_ws;
    unsigned char*  wf8 = (unsigned char*)(wf + OFF_F8);

    conv_b0<<<(SZ_B0 + 255) / 256, 256, 0, stream>>>(wk, wf);
    conv_b8<<<(SZ_F8B + 255) / 256, 256, 0, stream>>>(wr, wf8);
    conv_gen<<<(SZ_M1 + 255) / 256, 256, 0, stream>>>(w1, wf + OFF_M1, 50, 50, 2, SZ_M1);
    conv_gen<<<(SZ_M2 + 255) / 256, 256, 0, stream>>>(w2, wf + OFF_M2, 50, 24, 2, SZ_M2);
    conv_heads<<<(SZ_H + 255) / 256, 256, 0, stream>>>(wa, wm, wsg, wf);
    dilstm<<<NBLK, NT, 0, stream>>>(x, wf, bz, b1, b2, ba, bm, bs, out);
}